// Round 16
// baseline (1192.199 us; speedup 1.0000x reference)
//
#include <hip/hip_runtime.h>
#include <math.h>

#define NB 64
#define NA 256
#define NM 16
#define HA 256
#define NF 16
#define NCONV 3
#define NCLS 6
#define EPSB 1e-5f

typedef __attribute__((ext_vector_type(8))) short short8v;   // 8 bf16 (4 VGPR)
typedef __attribute__((ext_vector_type(4))) float f32x4;

__device__ __forceinline__ short f2bf(float x) {
  union { float f; unsigned u; } v; v.f = x;
  unsigned r = v.u + 0x7fff + ((v.u >> 16) & 1);  // RTNE
  return (short)(r >> 16);
}

// ---------------- prep: WT bf16 [l][1024][256] + W3bf bf16 [l][512 o][16 k] ----------------
__global__ void prep_weights(const float* __restrict__ Wf,
                             short* __restrict__ WT, short* __restrict__ W3bf) {
  int i = blockIdx.x * 256 + threadIdx.x;
  const int TOT1 = NCONV * 1024 * 256;
  if (i < TOT1) {
    int l = i / (1024 * 256);
    int r = i - l * (1024 * 256);
    int o = r >> 8, k = r & 255;
    float w = (o < 512) ? Wf[(l * 528 + k) * 512 + o]
                        : Wf[(l * 528 + 256 + k) * 512 + (o - 512)];
    WT[i] = f2bf(w);
  }
  const int TOT2 = NCONV * 512 * NF;  // [l][o][k]
  if (i < TOT2) {
    int l = i / (512 * NF);
    int r = i - l * (512 * NF);
    int o = r >> 4, k = r & 15;
    W3bf[i] = f2bf(Wf[(l * 528 + 512 + k) * 512 + o]);
  }
}

// fused init: gauss (bf16), atom copy, emb bf16 — one 4.19M-element grid
__global__ void init_all(const float* __restrict__ dist, const float* __restrict__ emb,
                         short* __restrict__ Gbf, float* __restrict__ atom,
                         short* __restrict__ ebf) {
  int i = blockIdx.x * 256 + threadIdx.x;
  {  // gauss
    int r = i >> 4, f = i & 15;
    float d = dist[r];
    float x = d - 0.2f * (float)f;
    Gbf[i] = f2bf(__expf(-x * x * 25.0f));
  }
  {  // atom broadcast copy
    atom[i] = emb[i & (NA * HA - 1)];
  }
  if (i < NA * HA) {  // emb bf16
    ebf[i] = f2bf(emb[i]);
  }
}

// ---------------- MFMA GEMM: C[M][1024] f32 = Abf[M][256] @ WT^T ----------------
__global__ __launch_bounds__(256) void gemm_mfma(const short* __restrict__ Abf,
                                                 const short* __restrict__ WT,
                                                 float* __restrict__ C, int Mrows) {
  __shared__ short As[128][72];
  __shared__ short Bs[128][72];
  int t = threadIdx.x;
  int wave = t >> 6, lane = t & 63;
  int wr = wave >> 1, wc = wave & 1;
  int l16 = lane & 15, lhi = lane >> 4;

  int wg = blockIdx.x;
  int nRowBlocks = Mrows >> 7;
  int rowBlock, colBlock;
  if (nRowBlocks >= 8) {
    rowBlock = (wg & 7) + ((wg >> 6) << 3);
    colBlock = (wg >> 3) & 7;
  } else {
    rowBlock = wg % nRowBlocks;
    colBlock = wg / nRowBlocks;
  }
  int rowBase = rowBlock << 7, colBase = colBlock << 7;

  f32x4 acc[4][4];
#pragma unroll
  for (int i = 0; i < 4; ++i)
#pragma unroll
    for (int j = 0; j < 4; ++j) acc[i][j] = (f32x4)(0.f);

  for (int k0 = 0; k0 < 256; k0 += 64) {
#pragma unroll
    for (int cc = 0; cc < 4; ++cc) {
      int c = t + cc * 256;
      int row = c >> 3, ko = (c & 7) << 3;
      *(int4*)&As[row][ko] = *(const int4*)&Abf[(size_t)(rowBase + row) * 256 + k0 + ko];
      *(int4*)&Bs[row][ko] = *(const int4*)&WT[(size_t)(colBase + row) * 256 + k0 + ko];
    }
    __syncthreads();
#pragma unroll
    for (int ks = 0; ks < 2; ++ks) {
      int kk = ks * 32 + lhi * 8;
      short8v a[4], b[4];
#pragma unroll
      for (int f = 0; f < 4; ++f) {
        a[f] = *(const short8v*)&As[wr * 64 + f * 16 + l16][kk];
        b[f] = *(const short8v*)&Bs[wc * 64 + f * 16 + l16][kk];
      }
#pragma unroll
      for (int i = 0; i < 4; ++i)
#pragma unroll
        for (int j = 0; j < 4; ++j)
          acc[i][j] = __builtin_amdgcn_mfma_f32_16x16x32_bf16(a[i], b[j], acc[i][j], 0, 0, 0);
    }
    __syncthreads();
  }
#pragma unroll
  for (int i = 0; i < 4; ++i) {
#pragma unroll
    for (int j = 0; j < 4; ++j) {
      int col = colBase + wc * 64 + j * 16 + l16;
      int row0 = rowBase + wr * 64 + i * 16 + lhi * 4;
#pragma unroll
      for (int r = 0; r < 4; ++r)
        C[(size_t)(row0 + r) * 1024 + col] = acc[i][j][r];
    }
  }
}

// ---------------- block decode: 4096 wgs (2 o-halves), XCD-pinned ----------------
// wg = (((bhi*32 + ng)*2 + hf)*8) + x : b = bhi*8 + x, n0 = ng*8, half = hf
__device__ __forceinline__ void decode_wg_h(int wg, int& b, int& n0, int& hf) {
  int x = wg & 7;
  int t2 = wg >> 3;
  hf = t2 & 1;
  n0 = ((t2 >> 1) & 31) * 8;
  b = (t2 >> 6) * 8 + x;
}

// ---------------- unified MFMA pass: o-split halves per-thread state -----------------------
// PASS=0 -> BN1 stats; PASS=1 -> BN apply + sigmoid*relu + m-sum + BN2 stats.
// Each wave owns 32 filter cols (c0..c0+31) + their paired core cols (+256):
// 4 MFMA tiles (j<2 filter, j>=2 core), acc[4] (16 regs). Per-thread state ~half of
// round-11's 68-reg body -> fits (256,4)'s 64-reg cap without spill.
// Tripwire: WRITE_SIZE ~20 MB; spill signature is WRITE >> 100 MB (rounds 9/10/12/14/15).
template <int PASS>
__global__ __launch_bounds__(256, 4) void pass_mfma(const float* __restrict__ H,
                                                    const short* __restrict__ Gbf,
                                                    const int* __restrict__ adj,
                                                    const short* __restrict__ W3bf,
                                                    const float* __restrict__ coef,
                                                    float* __restrict__ nbr,
                                                    float* __restrict__ stats,
                                                    int batched) {
  __shared__ int jis[128];
  __shared__ float cf[1024];

  int t = threadIdx.x;
  int b, n0, hf;
  decode_wg_h(blockIdx.x, b, n0, hf);
  int hbase = batched ? b * NA : 0;

  if (t < 128) jis[t] = adj[(b * NA + n0) * NM + t];
  if (PASS == 1) {
    cf[t] = coef[t]; cf[256 + t] = coef[256 + t];
    cf[512 + t] = coef[512 + t]; cf[768 + t] = coef[768 + t];
  }
  __syncthreads();

  int lane = t & 63, wv = t >> 6;
  int l16 = lane & 15, lhi = lane >> 4;
  const short8v zv = {0, 0, 0, 0, 0, 0, 0, 0};
  int c0 = hf * 128 + wv * 32;  // wave's filter col base (32 cols)

  // 4 tiles: j<2 -> filter cols c0+j*16+l16 ; j>=2 -> core cols +256
  short8v bfm[4];
  int oc[4];
#pragma unroll
  for (int j = 0; j < 4; ++j) {
    int col = c0 + (j & 1) * 16 + l16 + ((j >= 2) ? 256 : 0);
    oc[j] = col;
    bfm[j] = (lhi < 2) ? *(const short8v*)&W3bf[(size_t)col * NF + lhi * 8] : zv;
  }

  float scf[2], shf[2], scc[2], shc[2];
  if (PASS == 1) {
#pragma unroll
    for (int p = 0; p < 2; ++p) {
      scf[p] = cf[oc[p]];       shf[p] = cf[512 + oc[p]];
      scc[p] = cf[oc[p + 2]];   shc[p] = cf[512 + oc[p + 2]];
    }
  }

  float s1f[2] = {0, 0}, s2f[2] = {0, 0};
  float s1c[2] = {0, 0}, s2c[2] = {0, 0};
  float sB1[2] = {0, 0}, sB2[2] = {0, 0};

  for (int nn = 0; nn < 8; ++nn) {
    int n = n0 + nn;
    short8v af = (lhi < 2)
        ? *(const short8v*)&Gbf[(((size_t)(b * NA + n)) * NM + l16) * NF + lhi * 8]
        : zv;
    f32x4 acc[4];
#pragma unroll
    for (int j = 0; j < 4; ++j) acc[j] = (f32x4)(0.f);
#pragma unroll
    for (int j = 0; j < 4; ++j)
      acc[j] = __builtin_amdgcn_mfma_f32_16x16x32_bf16(af, bfm[j], acc[j], 0, 0, 0);

    int jv[4];
#pragma unroll
    for (int r = 0; r < 4; ++r) jv[r] = jis[nn * 16 + lhi * 4 + r];  // m = lhi*4+r
    const float* hs = &H[(size_t)(hbase + n) * 1024];
    float x1v[4];
#pragma unroll
    for (int j = 0; j < 4; ++j) x1v[j] = hs[oc[j]];
    float yv[4][4];
#pragma unroll
    for (int j = 0; j < 4; ++j)
#pragma unroll
      for (int r = 0; r < 4; ++r)
        yv[j][r] = H[(size_t)(hbase + jv[r]) * 1024 + 512 + oc[j]];

    if (PASS == 0) {
#pragma unroll
      for (int p = 0; p < 2; ++p) {
#pragma unroll
        for (int r = 0; r < 4; ++r) {
          float zf = acc[p][r] + x1v[p] + yv[p][r];
          float zc = acc[p + 2][r] + x1v[p + 2] + yv[p + 2][r];
          s1f[p] += zf; s2f[p] = fmaf(zf, zf, s2f[p]);
          s1c[p] += zc; s2c[p] = fmaf(zc, zc, s2c[p]);
        }
      }
    } else {
#pragma unroll
      for (int p = 0; p < 2; ++p) {
        float ps = 0.f;
#pragma unroll
        for (int r = 0; r < 4; ++r) {
          float zf = acc[p][r] + x1v[p] + yv[p][r];
          float zc = acc[p + 2][r] + x1v[p + 2] + yv[p + 2][r];
          float yfv = fmaf(zf, scf[p], shf[p]);
          float ycv = fmaf(zc, scc[p], shc[p]);
          float sig = 1.0f / (1.0f + __expf(-yfv));
          ps = fmaf(sig, fmaxf(ycv, 0.f), ps);
        }
        ps += __shfl_xor(ps, 16);
        ps += __shfl_xor(ps, 32);
        if (lhi == 0) {
          nbr[(size_t)(b * NA + n) * HA + oc[p]] = ps;
          sB1[p] += ps; sB2[p] = fmaf(ps, ps, sB2[p]);
        }
      }
    }
  }

  if (PASS == 0) {
#pragma unroll
    for (int p = 0; p < 2; ++p) {
      float v;
      v = s1f[p]; v += __shfl_xor(v, 16); v += __shfl_xor(v, 32);
      if (lhi == 0) atomicAdd(&stats[oc[p]], v);
      v = s2f[p]; v += __shfl_xor(v, 16); v += __shfl_xor(v, 32);
      if (lhi == 0) atomicAdd(&stats[512 + oc[p]], v);
      v = s1c[p]; v += __shfl_xor(v, 16); v += __shfl_xor(v, 32);
      if (lhi == 0) atomicAdd(&stats[oc[p + 2]], v);
      v = s2c[p]; v += __shfl_xor(v, 16); v += __shfl_xor(v, 32);
      if (lhi == 0) atomicAdd(&stats[512 + oc[p + 2]], v);
    }
  } else {
#pragma unroll
    for (int p = 0; p < 2; ++p) {
      if (lhi == 0) {
        atomicAdd(&stats[oc[p]], sB1[p]);
        atomicAdd(&stats[256 + oc[p]], sB2[p]);
      }
    }
  }
}

__global__ void finalize1(const float* __restrict__ bn1, const float* __restrict__ g,
                          const float* __restrict__ beta, float* __restrict__ coef) {
  int t = threadIdx.x;  // 512
  const float inv = 1.0f / (float)(NB * NA * NM);
  float mu = bn1[t] * inv;
  float var = bn1[512 + t] * inv - mu * mu;
  float sc = g[t] * rsqrtf(var + EPSB);
  coef[t] = sc;
  coef[512 + t] = beta[t] - mu * sc;
}

__global__ void finalize2(const float* __restrict__ bn2, const float* __restrict__ g,
                          const float* __restrict__ beta, float* __restrict__ coef2) {
  int t = threadIdx.x;  // 256
  const float inv = 1.0f / (float)(NB * NA);
  float mu = bn2[t] * inv;
  float var = bn2[256 + t] * inv - mu * mu;
  float sc = g[t] * rsqrtf(var + EPSB);
  coef2[t] = sc;
  coef2[256 + t] = beta[t] - mu * sc;
}

// pass_c: atom = relu(atom + nbr*sc + sh); emit bf16 copy for next layer's GEMM A
__global__ void pass_c(float4* __restrict__ atom, const float4* __restrict__ nbr,
                       const float* __restrict__ coef2, short* __restrict__ abf) {
  int i = blockIdx.x * 256 + threadIdx.x;
  int o = (i & 63) * 4;
  float4 a = atom[i];
  float4 nv = nbr[i];
  a.x = fmaxf(a.x + fmaf(nv.x, coef2[o + 0], coef2[256 + o + 0]), 0.f);
  a.y = fmaxf(a.y + fmaf(nv.y, coef2[o + 1], coef2[256 + o + 1]), 0.f);
  a.z = fmaxf(a.z + fmaf(nv.z, coef2[o + 2], coef2[256 + o + 2]), 0.f);
  a.w = fmaxf(a.w + fmaf(nv.w, coef2[o + 3], coef2[256 + o + 3]), 0.f);
  atom[i] = a;
  short4 s;
  s.x = f2bf(a.x); s.y = f2bf(a.y); s.z = f2bf(a.z); s.w = f2bf(a.w);
  *(short4*)&abf[(size_t)i * 4] = s;
}

// ---------------- epilogue ----------------
__global__ __launch_bounds__(256) void epilogue(const float* __restrict__ atom,
                                                const float* __restrict__ Wc,
                                                const float* __restrict__ bc,
                                                float* __restrict__ out) {
  __shared__ float pooled[HA];
  __shared__ float lg[NCLS];
  int b = blockIdx.x, t = threadIdx.x;
  float s = 0.f;
  for (int n = 0; n < NA; ++n) s += atom[(size_t)(b * NA + n) * HA + t];
  pooled[t] = s * (1.0f / (float)NA);
  __syncthreads();
  if (t < NCLS) {
    float a = bc[t];
    for (int o = 0; o < HA; ++o) a += pooled[o] * Wc[o * NCLS + t];
    lg[t] = a;
  }
  __syncthreads();
  if (t == 0) {
    float mx = lg[0];
    for (int c = 1; c < NCLS; ++c) mx = fmaxf(mx, lg[c]);
    float e[NCLS], den = 0.f;
    for (int c = 0; c < NCLS; ++c) { e[c] = __expf(lg[c] - mx); den += e[c]; }
    for (int c = 0; c < NCLS; ++c) out[b * NCLS + c] = e[c] / den;
  }
}

extern "C" void kernel_launch(void* const* d_in, const int* in_sizes, int n_in,
                              void* d_out, int out_size, void* d_ws, size_t ws_size,
                              hipStream_t stream) {
  const float* dist = (const float*)d_in[0];
  const int* adj = (const int*)d_in[1];
  const float* emb = (const float*)d_in[2];
  const float* Wf = (const float*)d_in[3];
  const float* gh = (const float*)d_in[5];
  const float* bh = (const float*)d_in[6];
  const float* go = (const float*)d_in[7];
  const float* bo = (const float*)d_in[8];
  const float* Wc = (const float*)d_in[9];
  const float* bc = (const float*)d_in[10];
  float* out = (float*)d_out;

  char* p = (char*)d_ws;
  short* Gbf = (short*)p;   p += (size_t)NB * NA * NM * NF * 2;   // 8 MB
  float* H = (float*)p;     p += (size_t)NB * NA * 1024 * 4;      // 64 MB
  float* H0 = (float*)p;    p += (size_t)NA * 1024 * 4;           // 1 MB
  float* atom = (float*)p;  p += (size_t)NB * NA * HA * 4;        // 16 MB
  float* nbr = (float*)p;   p += (size_t)NB * NA * HA * 4;        // 16 MB
  short* WT = (short*)p;    p += (size_t)NCONV * 1024 * 256 * 2;  // 1.5 MB
  short* Abf = (short*)p;   p += (size_t)NB * NA * 256 * 2;       // 8 MB
  short* Ebf = (short*)p;   p += (size_t)NA * 256 * 2;            // 128 KB
  short* W3bf = (short*)p;  p += (size_t)NCONV * 512 * NF * 2;    // 48 KB
  float* bn1 = (float*)p;   p += 1024 * 4;
  float* bn2 = (float*)p;   p += 512 * 4;
  float* coef1 = (float*)p; p += 1024 * 4;
  float* coef2 = (float*)p; p += 512 * 4;

  prep_weights<<<3072, 256, 0, stream>>>(Wf, WT, W3bf);
  init_all<<<16384, 256, 0, stream>>>(dist, emb, Gbf, atom, Ebf);

  for (int l = 0; l < NCONV; ++l) {
    hipMemsetAsync(bn1, 0, (1024 + 512) * 4, stream);
    int Mrows = (l == 0) ? NA : NB * NA;
    const short* Amat = (l == 0) ? Ebf : Abf;
    float* Hl = (l == 0) ? H0 : H;
    gemm_mfma<<<(Mrows / 128) * 8, 256, 0, stream>>>(Amat, WT + (size_t)l * 1024 * 256, Hl, Mrows);
    pass_mfma<0><<<4096, 256, 0, stream>>>(Hl, Gbf, adj, W3bf + (size_t)l * 512 * NF,
                                           nullptr, nullptr, bn1, l > 0);
    finalize1<<<1, 512, 0, stream>>>(bn1, gh + l * 512, bh + l * 512, coef1);
    pass_mfma<1><<<4096, 256, 0, stream>>>(Hl, Gbf, adj, W3bf + (size_t)l * 512 * NF,
                                           coef1, nbr, bn2, l > 0);
    finalize2<<<1, 256, 0, stream>>>(bn2, go + l * 256, bo + l * 256, coef2);
    pass_c<<<4096, 256, 0, stream>>>((float4*)atom, (const float4*)nbr, coef2, Abf);
  }
  epilogue<<<NB, 256, 0, stream>>>(atom, Wc, bc, out);
}

// Round 17
// 539.547 us; speedup vs baseline: 2.2096x; 2.2096x over previous
//
#include <hip/hip_runtime.h>
#include <math.h>

#define NB 64
#define NA 256
#define NM 16
#define HA 256
#define NF 16
#define NCONV 3
#define NCLS 6
#define EPSB 1e-5f

typedef __attribute__((ext_vector_type(8))) short short8v;   // 8 bf16 (4 VGPR)
typedef __attribute__((ext_vector_type(4))) float f32x4;

__device__ __forceinline__ short f2bf(float x) {
  union { float f; unsigned u; } v; v.f = x;
  unsigned r = v.u + 0x7fff + ((v.u >> 16) & 1);  // RTNE
  return (short)(r >> 16);
}

// ---------------- prep: WT bf16 [l][1024][256] + W3bf bf16 [l][512 o][16 k] ----------------
__global__ void prep_weights(const float* __restrict__ Wf,
                             short* __restrict__ WT, short* __restrict__ W3bf) {
  int i = blockIdx.x * 256 + threadIdx.x;
  const int TOT1 = NCONV * 1024 * 256;
  if (i < TOT1) {
    int l = i / (1024 * 256);
    int r = i - l * (1024 * 256);
    int o = r >> 8, k = r & 255;
    float w = (o < 512) ? Wf[(l * 528 + k) * 512 + o]
                        : Wf[(l * 528 + 256 + k) * 512 + (o - 512)];
    WT[i] = f2bf(w);
  }
  const int TOT2 = NCONV * 512 * NF;  // [l][o][k]
  if (i < TOT2) {
    int l = i / (512 * NF);
    int r = i - l * (512 * NF);
    int o = r >> 4, k = r & 15;
    W3bf[i] = f2bf(Wf[(l * 528 + 512 + k) * 512 + o]);
  }
}

// fused init: gauss (bf16), atom copy, emb bf16 — one 4.19M-element grid
__global__ void init_all(const float* __restrict__ dist, const float* __restrict__ emb,
                         short* __restrict__ Gbf, float* __restrict__ atom,
                         short* __restrict__ ebf) {
  int i = blockIdx.x * 256 + threadIdx.x;
  {  // gauss
    int r = i >> 4, f = i & 15;
    float d = dist[r];
    float x = d - 0.2f * (float)f;
    Gbf[i] = f2bf(__expf(-x * x * 25.0f));
  }
  {  // atom broadcast copy
    atom[i] = emb[i & (NA * HA - 1)];
  }
  if (i < NA * HA) {  // emb bf16
    ebf[i] = f2bf(emb[i]);
  }
}

// ---------------- MFMA GEMM: C[M][1024] f32 = Abf[M][256] @ WT^T ----------------
__global__ __launch_bounds__(256) void gemm_mfma(const short* __restrict__ Abf,
                                                 const short* __restrict__ WT,
                                                 float* __restrict__ C, int Mrows) {
  __shared__ short As[128][72];
  __shared__ short Bs[128][72];
  int t = threadIdx.x;
  int wave = t >> 6, lane = t & 63;
  int wr = wave >> 1, wc = wave & 1;
  int l16 = lane & 15, lhi = lane >> 4;

  int wg = blockIdx.x;
  int nRowBlocks = Mrows >> 7;
  int rowBlock, colBlock;
  if (nRowBlocks >= 8) {
    rowBlock = (wg & 7) + ((wg >> 6) << 3);
    colBlock = (wg >> 3) & 7;
  } else {
    rowBlock = wg % nRowBlocks;
    colBlock = wg / nRowBlocks;
  }
  int rowBase = rowBlock << 7, colBase = colBlock << 7;

  f32x4 acc[4][4];
#pragma unroll
  for (int i = 0; i < 4; ++i)
#pragma unroll
    for (int j = 0; j < 4; ++j) acc[i][j] = (f32x4)(0.f);

  for (int k0 = 0; k0 < 256; k0 += 64) {
#pragma unroll
    for (int cc = 0; cc < 4; ++cc) {
      int c = t + cc * 256;
      int row = c >> 3, ko = (c & 7) << 3;
      *(int4*)&As[row][ko] = *(const int4*)&Abf[(size_t)(rowBase + row) * 256 + k0 + ko];
      *(int4*)&Bs[row][ko] = *(const int4*)&WT[(size_t)(colBase + row) * 256 + k0 + ko];
    }
    __syncthreads();
#pragma unroll
    for (int ks = 0; ks < 2; ++ks) {
      int kk = ks * 32 + lhi * 8;
      short8v a[4], b[4];
#pragma unroll
      for (int f = 0; f < 4; ++f) {
        a[f] = *(const short8v*)&As[wr * 64 + f * 16 + l16][kk];
        b[f] = *(const short8v*)&Bs[wc * 64 + f * 16 + l16][kk];
      }
#pragma unroll
      for (int i = 0; i < 4; ++i)
#pragma unroll
        for (int j = 0; j < 4; ++j)
          acc[i][j] = __builtin_amdgcn_mfma_f32_16x16x32_bf16(a[i], b[j], acc[i][j], 0, 0, 0);
    }
    __syncthreads();
  }
#pragma unroll
  for (int i = 0; i < 4; ++i) {
#pragma unroll
    for (int j = 0; j < 4; ++j) {
      int col = colBase + wc * 64 + j * 16 + l16;
      int row0 = rowBase + wr * 64 + i * 16 + lhi * 4;
#pragma unroll
      for (int r = 0; r < 4; ++r)
        C[(size_t)(row0 + r) * 1024 + col] = acc[i][j][r];
    }
  }
}

// ---------------- XCD-swizzled block decode for passes (2048 wgs, 8 n's each) -------------
__device__ __forceinline__ void decode_wg(int wg, int& b, int& n0) {
  int x = wg & 7;
  int t2 = wg >> 3;
  int ng = t2 & 31;
  int bhi = t2 >> 5;
  b = bhi * 8 + x;
  n0 = ng * 8;
}

// ---------------- unified MFMA pass (round-11 proven structure, FINAL) ----------------
// PASS=0 -> BN1 stats; PASS=1 -> BN apply + sigmoid*relu + m-sum + BN2 stats.
// W3/G MFMA fragments direct from global (16B chunks), k 16..31 zero. acc[8] (32 regs).
// STABILITY NOTE (rounds 9-16): this body needs 68 VGPR and must NOT be perturbed:
//  - compact/float4 bodies or trip-count<8 -> full unroll -> live-range spill
//    (WRITE_SIZE 0.5-0.9 GB: rounds 9,10,12,16)
//  - #pragma unroll 1 -> serialization (VALUBusy 19%: round 13)
//  - VGPR cap <68 via launch_bounds (256,4)/(64,7) -> forced spill (rounds 14,15)
// (256,3) = 3 waves/SIMD, VGPR 68, no spill, 81 us/dispatch: the stable optimum.
template <int PASS>
__global__ __launch_bounds__(256, 3) void pass_mfma(const float* __restrict__ H,
                                                    const short* __restrict__ Gbf,
                                                    const int* __restrict__ adj,
                                                    const short* __restrict__ W3bf,
                                                    const float* __restrict__ coef,
                                                    float* __restrict__ nbr,
                                                    float* __restrict__ stats,
                                                    int batched) {
  __shared__ int jis[128];
  __shared__ float cf[1024];

  int t = threadIdx.x;
  int b, n0;
  decode_wg(blockIdx.x, b, n0);
  int hbase = batched ? b * NA : 0;

  if (t < 128) jis[t] = adj[(b * NA + n0) * NM + t];
  if (PASS == 1) {
    cf[t] = coef[t]; cf[256 + t] = coef[256 + t];
    cf[512 + t] = coef[512 + t]; cf[768 + t] = coef[768 + t];
  }
  __syncthreads();

  int lane = t & 63, wv = t >> 6;
  int l16 = lane & 15, lhi = lane >> 4;
  const short8v zv = {0, 0, 0, 0, 0, 0, 0, 0};

  // B-fragments direct from global: col oc[j], k = lhi*8 (lhi<2), else zero pad
  short8v bfm[8];
  int oc[8];
#pragma unroll
  for (int j = 0; j < 8; ++j) {
    int col = wv * 64 + (j & 3) * 16 + l16 + ((j >= 4) ? 256 : 0);
    oc[j] = col;
    bfm[j] = (lhi < 2) ? *(const short8v*)&W3bf[(size_t)col * NF + lhi * 8] : zv;
  }

  float scf[4], shf[4], scc[4], shc[4];
  if (PASS == 1) {
#pragma unroll
    for (int p = 0; p < 4; ++p) {
      scf[p] = cf[oc[p]];       shf[p] = cf[512 + oc[p]];
      scc[p] = cf[oc[p + 4]];   shc[p] = cf[512 + oc[p + 4]];
    }
  }

  float s1f[4] = {0, 0, 0, 0}, s2f[4] = {0, 0, 0, 0};
  float s1c[4] = {0, 0, 0, 0}, s2c[4] = {0, 0, 0, 0};
  float sB1[4] = {0, 0, 0, 0}, sB2[4] = {0, 0, 0, 0};

  for (int nn = 0; nn < 8; ++nn) {
    int n = n0 + nn;
    // A-fragment direct from global: rows m = l16 of G for this n
    short8v af = (lhi < 2)
        ? *(const short8v*)&Gbf[(((size_t)(b * NA + n)) * NM + l16) * NF + lhi * 8]
        : zv;
    f32x4 acc[8];
#pragma unroll
    for (int j = 0; j < 8; ++j) acc[j] = (f32x4)(0.f);
#pragma unroll
    for (int j = 0; j < 8; ++j)
      acc[j] = __builtin_amdgcn_mfma_f32_16x16x32_bf16(af, bfm[j], acc[j], 0, 0, 0);

    int jv[4];
#pragma unroll
    for (int r = 0; r < 4; ++r) jv[r] = jis[nn * 16 + lhi * 4 + r];  // m = lhi*4+r
    const float* hs = &H[(size_t)(hbase + n) * 1024];
    float x1v[8];
#pragma unroll
    for (int j = 0; j < 8; ++j) x1v[j] = hs[oc[j]];
    float yv[8][4];
#pragma unroll
    for (int j = 0; j < 8; ++j)
#pragma unroll
      for (int r = 0; r < 4; ++r)
        yv[j][r] = H[(size_t)(hbase + jv[r]) * 1024 + 512 + oc[j]];

    if (PASS == 0) {
#pragma unroll
      for (int p = 0; p < 4; ++p) {
#pragma unroll
        for (int r = 0; r < 4; ++r) {
          float zf = acc[p][r] + x1v[p] + yv[p][r];
          float zc = acc[p + 4][r] + x1v[p + 4] + yv[p + 4][r];
          s1f[p] += zf; s2f[p] = fmaf(zf, zf, s2f[p]);
          s1c[p] += zc; s2c[p] = fmaf(zc, zc, s2c[p]);
        }
      }
    } else {
#pragma unroll
      for (int p = 0; p < 4; ++p) {
        float ps = 0.f;
#pragma unroll
        for (int r = 0; r < 4; ++r) {
          float zf = acc[p][r] + x1v[p] + yv[p][r];
          float zc = acc[p + 4][r] + x1v[p + 4] + yv[p + 4][r];
          float yfv = fmaf(zf, scf[p], shf[p]);
          float ycv = fmaf(zc, scc[p], shc[p]);
          float sig = 1.0f / (1.0f + __expf(-yfv));
          ps = fmaf(sig, fmaxf(ycv, 0.f), ps);
        }
        ps += __shfl_xor(ps, 16);
        ps += __shfl_xor(ps, 32);
        if (lhi == 0) {
          nbr[(size_t)(b * NA + n) * HA + oc[p]] = ps;
          sB1[p] += ps; sB2[p] = fmaf(ps, ps, sB2[p]);
        }
      }
    }
  }

  if (PASS == 0) {
#pragma unroll
    for (int p = 0; p < 4; ++p) {
      float v;
      v = s1f[p]; v += __shfl_xor(v, 16); v += __shfl_xor(v, 32);
      if (lhi == 0) atomicAdd(&stats[oc[p]], v);
      v = s2f[p]; v += __shfl_xor(v, 16); v += __shfl_xor(v, 32);
      if (lhi == 0) atomicAdd(&stats[512 + oc[p]], v);
      v = s1c[p]; v += __shfl_xor(v, 16); v += __shfl_xor(v, 32);
      if (lhi == 0) atomicAdd(&stats[oc[p + 4]], v);
      v = s2c[p]; v += __shfl_xor(v, 16); v += __shfl_xor(v, 32);
      if (lhi == 0) atomicAdd(&stats[512 + oc[p + 4]], v);
    }
  } else {
#pragma unroll
    for (int p = 0; p < 4; ++p) {
      if (lhi == 0) {
        atomicAdd(&stats[oc[p]], sB1[p]);
        atomicAdd(&stats[256 + oc[p]], sB2[p]);
      }
    }
  }
}

__global__ void finalize1(const float* __restrict__ bn1, const float* __restrict__ g,
                          const float* __restrict__ beta, float* __restrict__ coef) {
  int t = threadIdx.x;  // 512
  const float inv = 1.0f / (float)(NB * NA * NM);
  float mu = bn1[t] * inv;
  float var = bn1[512 + t] * inv - mu * mu;
  float sc = g[t] * rsqrtf(var + EPSB);
  coef[t] = sc;
  coef[512 + t] = beta[t] - mu * sc;
}

__global__ void finalize2(const float* __restrict__ bn2, const float* __restrict__ g,
                          const float* __restrict__ beta, float* __restrict__ coef2) {
  int t = threadIdx.x;  // 256
  const float inv = 1.0f / (float)(NB * NA);
  float mu = bn2[t] * inv;
  float var = bn2[256 + t] * inv - mu * mu;
  float sc = g[t] * rsqrtf(var + EPSB);
  coef2[t] = sc;
  coef2[256 + t] = beta[t] - mu * sc;
}

// pass_c: atom = relu(atom + nbr*sc + sh); emit bf16 copy for next layer's GEMM A
__global__ void pass_c(float4* __restrict__ atom, const float4* __restrict__ nbr,
                       const float* __restrict__ coef2, short* __restrict__ abf) {
  int i = blockIdx.x * 256 + threadIdx.x;
  int o = (i & 63) * 4;
  float4 a = atom[i];
  float4 nv = nbr[i];
  a.x = fmaxf(a.x + fmaf(nv.x, coef2[o + 0], coef2[256 + o + 0]), 0.f);
  a.y = fmaxf(a.y + fmaf(nv.y, coef2[o + 1], coef2[256 + o + 1]), 0.f);
  a.z = fmaxf(a.z + fmaf(nv.z, coef2[o + 2], coef2[256 + o + 2]), 0.f);
  a.w = fmaxf(a.w + fmaf(nv.w, coef2[o + 3], coef2[256 + o + 3]), 0.f);
  atom[i] = a;
  short4 s;
  s.x = f2bf(a.x); s.y = f2bf(a.y); s.z = f2bf(a.z); s.w = f2bf(a.w);
  *(short4*)&abf[(size_t)i * 4] = s;
}

// ---------------- epilogue ----------------
__global__ __launch_bounds__(256) void epilogue(const float* __restrict__ atom,
                                                const float* __restrict__ Wc,
                                                const float* __restrict__ bc,
                                                float* __restrict__ out) {
  __shared__ float pooled[HA];
  __shared__ float lg[NCLS];
  int b = blockIdx.x, t = threadIdx.x;
  float s = 0.f;
  for (int n = 0; n < NA; ++n) s += atom[(size_t)(b * NA + n) * HA + t];
  pooled[t] = s * (1.0f / (float)NA);
  __syncthreads();
  if (t < NCLS) {
    float a = bc[t];
    for (int o = 0; o < HA; ++o) a += pooled[o] * Wc[o * NCLS + t];
    lg[t] = a;
  }
  __syncthreads();
  if (t == 0) {
    float mx = lg[0];
    for (int c = 1; c < NCLS; ++c) mx = fmaxf(mx, lg[c]);
    float e[NCLS], den = 0.f;
    for (int c = 0; c < NCLS; ++c) { e[c] = __expf(lg[c] - mx); den += e[c]; }
    for (int c = 0; c < NCLS; ++c) out[b * NCLS + c] = e[c] / den;
  }
}

extern "C" void kernel_launch(void* const* d_in, const int* in_sizes, int n_in,
                              void* d_out, int out_size, void* d_ws, size_t ws_size,
                              hipStream_t stream) {
  const float* dist = (const float*)d_in[0];
  const int* adj = (const int*)d_in[1];
  const float* emb = (const float*)d_in[2];
  const float* Wf = (const float*)d_in[3];
  const float* gh = (const float*)d_in[5];
  const float* bh = (const float*)d_in[6];
  const float* go = (const float*)d_in[7];
  const float* bo = (const float*)d_in[8];
  const float* Wc = (const float*)d_in[9];
  const float* bc = (const float*)d_in[10];
  float* out = (float*)d_out;

  char* p = (char*)d_ws;
  short* Gbf = (short*)p;   p += (size_t)NB * NA * NM * NF * 2;   // 8 MB
  float* H = (float*)p;     p += (size_t)NB * NA * 1024 * 4;      // 64 MB
  float* H0 = (float*)p;    p += (size_t)NA * 1024 * 4;           // 1 MB
  float* atom = (float*)p;  p += (size_t)NB * NA * HA * 4;        // 16 MB
  float* nbr = (float*)p;   p += (size_t)NB * NA * HA * 4;        // 16 MB
  short* WT = (short*)p;    p += (size_t)NCONV * 1024 * 256 * 2;  // 1.5 MB
  short* Abf = (short*)p;   p += (size_t)NB * NA * 256 * 2;       // 8 MB
  short* Ebf = (short*)p;   p += (size_t)NA * 256 * 2;            // 128 KB
  short* W3bf = (short*)p;  p += (size_t)NCONV * 512 * NF * 2;    // 48 KB
  float* bn1 = (float*)p;   p += 1024 * 4;
  float* bn2 = (float*)p;   p += 512 * 4;
  float* coef1 = (float*)p; p += 1024 * 4;
  float* coef2 = (float*)p; p += 512 * 4;

  prep_weights<<<3072, 256, 0, stream>>>(Wf, WT, W3bf);
  init_all<<<16384, 256, 0, stream>>>(dist, emb, Gbf, atom, Ebf);

  for (int l = 0; l < NCONV; ++l) {
    hipMemsetAsync(bn1, 0, (1024 + 512) * 4, stream);
    int Mrows = (l == 0) ? NA : NB * NA;
    const short* Amat = (l == 0) ? Ebf : Abf;
    float* Hl = (l == 0) ? H0 : H;
    gemm_mfma<<<(Mrows / 128) * 8, 256, 0, stream>>>(Amat, WT + (size_t)l * 1024 * 256, Hl, Mrows);
    pass_mfma<0><<<2048, 256, 0, stream>>>(Hl, Gbf, adj, W3bf + (size_t)l * 512 * NF,
                                           nullptr, nullptr, bn1, l > 0);
    finalize1<<<1, 512, 0, stream>>>(bn1, gh + l * 512, bh + l * 512, coef1);
    pass_mfma<1><<<2048, 256, 0, stream>>>(Hl, Gbf, adj, W3bf + (size_t)l * 512 * NF,
                                           coef1, nbr, bn2, l > 0);
    finalize2<<<1, 256, 0, stream>>>(bn2, go + l * 256, bo + l * 256, coef2);
    pass_c<<<4096, 256, 0, stream>>>((float4*)atom, (const float4*)nbr, coef2, Abf);
  }
  epilogue<<<NB, 256, 0, stream>>>(atom, Wc, bc, out);
}